// Round 6
// baseline (341.140 us; speedup 1.0000x reference)
//
#include <hip/hip_runtime.h>
#include <math.h>

#define TOPK 100
#define HW 65536                   // 256*256
#define SLICE_STRIDE (7*HW)        // 458752
#define NBATCH 32
#define NBOX 200
#define HM (3*HW)                  // 196608 heatmap elems per slice
#define CAP 4096                   // candidate cap (no-ws fallback path)
#define SCAP 2048                  // candidate cap (per-slice path)
#define WS_NEED ((size_t)(64 * TOPK * 8))
#define TKEYS 0xC0400000u          // fkey(3.0f): per-slice collect threshold.
                                   // N(0,1): E[cand/slice]=265, sigma~16;
                                   // P(<100)~1e-24, P(>512)~1e-50. Exact
                                   // histogram fallback guards regardless.

// Order-preserving float->uint key: f1 > f2  <=>  key(f1) > key(f2)
__device__ __forceinline__ unsigned fkey(float f) {
    unsigned u = __float_as_uint(f);
    return (u & 0x80000000u) ? ~u : (u | 0x80000000u);
}

// Runtime-slot select over a 4-entry register array with constant indices only
__device__ __forceinline__ float sel4(const float a[4], int s) {
    float r = a[0];
    r = (s == 1) ? a[1] : r;
    r = (s == 2) ? a[2] : r;
    r = (s == 3) ? a[3] : r;
    return r;
}

// ---------------------------------------------------------------------------
// Wave64 u64 max-reduce via DPP (verbatim from round-4/5 verified kernels).
// ---------------------------------------------------------------------------
#if defined(__has_builtin) && __has_builtin(__builtin_amdgcn_update_dpp)
#define DPP64_STEP(ctrl)                                                        \
    {                                                                           \
        unsigned lo = (unsigned)x, hi = (unsigned)(x >> 32);                    \
        unsigned olo = (unsigned)__builtin_amdgcn_update_dpp((int)lo, (int)lo,  \
                                                             (ctrl), 0xF, 0xF, false); \
        unsigned ohi = (unsigned)__builtin_amdgcn_update_dpp((int)hi, (int)hi,  \
                                                             (ctrl), 0xF, 0xF, false); \
        unsigned long long o = ((unsigned long long)ohi << 32) | olo;           \
        x = (o > x) ? o : x;                                                    \
    }
__device__ __forceinline__ unsigned long long wave_umax64(unsigned long long x) {
    DPP64_STEP(0x111)   // row_shr:1
    DPP64_STEP(0x112)   // row_shr:2
    DPP64_STEP(0x114)   // row_shr:4
    DPP64_STEP(0x118)   // row_shr:8
    DPP64_STEP(0x142)   // row_bcast:15
    DPP64_STEP(0x143)   // row_bcast:31
    unsigned rlo = (unsigned)__builtin_amdgcn_readlane((int)(unsigned)x, 63);
    unsigned rhi = (unsigned)__builtin_amdgcn_readlane((int)(unsigned)(x >> 32), 63);
    return ((unsigned long long)rhi << 32) | rlo;
}
__device__ __forceinline__ float lane_getf(const float a[4], int slot, int lane) {
    return __uint_as_float((unsigned)__builtin_amdgcn_readlane(
        (int)__float_as_uint(sel4(a, slot)), lane));
}
#else
__device__ __forceinline__ unsigned long long wave_umax64(unsigned long long x) {
    #pragma unroll
    for (int off = 32; off > 0; off >>= 1) {
        unsigned long long o = __shfl_xor(x, off);
        if (o > x) x = o;
    }
    return x;
}
__device__ __forceinline__ float lane_getf(const float a[4], int slot, int lane) {
    return __shfl(sel4(a, slot), lane);
}
#endif

// ===========================================================================
// Kernel 1: exact SORTED top-100 per slice. 64 blocks x 1024 threads.
// FAST PATH: one streaming pass collecting keys >= TKEYS (no histogram, no
// scan). nc >= 100 proves top-100 subset. FALLBACK (nc<100 or overflow):
// exact histogram-threshold selection (round-2 verified logic, per slice).
// Key = (fkey(z) << 32) | ~idx  — identical ordering to all prior verified
// rounds (desc raw logit, ties -> lowest in-slice index).
// ===========================================================================
__global__ __launch_bounds__(1024) void kslice(const float* __restrict__ x,
                                               unsigned long long* __restrict__ ws) {
    __shared__ unsigned long long cand[SCAP];       // 16 KB (aliased: scan tmp)
    __shared__ unsigned hist[4096];                 // 16 KB (fallback only)
    __shared__ int shB, shB2;
    __shared__ unsigned shAbove, shNcand, shNc;

    const int slice = blockIdx.x;
    const int t = threadIdx.x;
    const float* xb = x + (size_t)slice * SLICE_STRIDE;
    const float4* xb4 = (const float4*)xb;
    const int N4 = HM / 4;                          // 49152

    if (t == 0) shNc = 0u;
    __syncthreads();

    // ---- fast path: single streaming collect over the whole slice ----
    #pragma unroll 4
    for (int i = t; i < N4; i += 1024) {
        float4 v = xb4[i];
        float a[4] = {v.x, v.y, v.z, v.w};
        #pragma unroll
        for (int q = 0; q < 4; ++q) {
            unsigned vk = fkey(a[q]);
            if (vk >= TKEYS) {
                unsigned pos = atomicAdd(&shNc, 1u);
                if (pos < SCAP)
                    cand[pos] = ((unsigned long long)vk << 32) |
                                (unsigned)~(unsigned)(i * 4 + q);
            }
        }
    }
    __syncthreads();
    unsigned nc = shNc;

    if (nc < TOPK || nc > SCAP) {
        // ---- exact fallback: histogram threshold (round-2 verified) ----
        if (t == 0) { shB = 0; shB2 = 0; shAbove = 0u; shNcand = 0u; shNc = 0u; }
        for (int i = t; i < 4096; i += 1024) hist[i] = 0u;
        __syncthreads();
        for (int i = t; i < N4; i += 1024) {
            float4 v = xb4[i];
            float a[4] = {v.x, v.y, v.z, v.w};
            #pragma unroll
            for (int q = 0; q < 4; ++q) atomicAdd(&hist[fkey(a[q]) >> 20], 1u);
        }
        __syncthreads();
        {
            unsigned* tmp = (unsigned*)cand;
            unsigned* src = hist;
            unsigned* dst = tmp;
            for (int d = 1; d < 4096; d <<= 1) {
                for (int i = t; i < 4096; i += 1024) {
                    unsigned v2 = src[i];
                    if (i + d < 4096) v2 += src[i + d];
                    dst[i] = v2;
                }
                __syncthreads();
                unsigned* sw = src; src = dst; dst = sw;
            }
            for (int i = t; i < 4096; i += 1024) {
                unsigned sb = src[i];
                unsigned sn = (i < 4095) ? src[i + 1] : 0u;
                if (sb >= TOPK && sn < TOPK) { shB = i; shAbove = sn; shNcand = sb; }
            }
            __syncthreads();
        }
        const bool refine = (shNcand > SCAP);
        if (refine) {
            for (int i = t; i < 4096; i += 1024) hist[i] = 0u;
            __syncthreads();
            const unsigned Bv = (unsigned)shB;
            for (int i = t; i < N4; i += 1024) {
                float4 v = xb4[i];
                float a[4] = {v.x, v.y, v.z, v.w};
                #pragma unroll
                for (int q = 0; q < 4; ++q) {
                    unsigned vk = fkey(a[q]);
                    if ((vk >> 20) == Bv) atomicAdd(&hist[(vk >> 8) & 0xFFFu], 1u);
                }
            }
            __syncthreads();
            if (t == 0) {
                unsigned need = TOPK - shAbove, cum = 0u;
                int b2 = 4095;
                for (; b2 >= 0; --b2) { cum += hist[b2]; if (cum >= need) break; }
                shB2 = (b2 < 0) ? 0 : b2;
            }
            __syncthreads();
        }
        {
            const unsigned Bv = (unsigned)shB;
            const unsigned B2v = refine ? (unsigned)shB2 : 0u;
            for (int i = t; i < N4; i += 1024) {
                float4 v = xb4[i];
                float a[4] = {v.x, v.y, v.z, v.w};
                #pragma unroll
                for (int q = 0; q < 4; ++q) {
                    unsigned vk = fkey(a[q]);
                    unsigned bin = vk >> 20;
                    bool ok = refine ? (bin > Bv || (bin == Bv && ((vk >> 8) & 0xFFFu) >= B2v))
                                     : (bin >= Bv);
                    if (ok) {
                        unsigned pos = atomicAdd(&shNc, 1u);
                        if (pos < SCAP)
                            cand[pos] = ((unsigned long long)vk << 32) |
                                        (unsigned)~(unsigned)(i * 4 + q);
                    }
                }
            }
            __syncthreads();
        }
        nc = shNc; if (nc > SCAP) nc = SCAP;
    }

    // ---- pad to pow2 and bitonic sort descending (64-bit keys) ----
    int P = 128; while (P < (int)nc) P <<= 1;       // <= 2048
    for (int i = (int)nc + t; i < P; i += 1024) cand[i] = 0ull;
    __syncthreads();
    for (int k = 2; k <= P; k <<= 1) {
        for (int j = k >> 1; j > 0; j >>= 1) {
            for (int i = t; i < P; i += 1024) {
                int ixj = i ^ j;
                if (ixj > i) {
                    unsigned long long a = cand[i], c2 = cand[ixj];
                    bool sw = ((i & k) == 0) ? (a < c2) : (a > c2);
                    if (sw) { cand[i] = c2; cand[ixj] = a; }
                }
            }
            __syncthreads();
        }
    }

    if (t < TOPK) ws[(size_t)slice * TOPK + t] = cand[t];
}

// ===========================================================================
// Kernel 2: 32 blocks x 256 threads. Decode 200 boxes straight from the
// per-slice sorted top-100 keys (no union sort), then wave-0 virtual-
// position soft-NMS: single 64-bit DPP reduce per round, pivot gathered via
// readlane (no LDS on the round critical path), exact zero-score early-out.
// ===========================================================================
__global__ __launch_bounds__(256) void knms5(const float* __restrict__ x,
                                             const unsigned long long* __restrict__ ws,
                                             float* __restrict__ out) {
    __shared__ float4 bxs4[NBOX];
    __shared__ float scs[NBOX];
    __shared__ float cl[NBOX];

    const int b = blockIdx.x, t = threadIdx.x;

    // ---- phase A: decode (rank order == verified sorted-key order) ----
    if (t < NBOX) {
        const int s = t / TOPK, rank = t - s * TOPK;
        const int slice = 2 * b + s;
        unsigned long long K = ws[(size_t)slice * TOPK + rank];
        unsigned vk = (unsigned)(K >> 32);
        unsigned idx = ~((unsigned)K);
        unsigned u = (vk & 0x80000000u) ? (vk & 0x7FFFFFFFu) : ~vk;
        float z = __uint_as_float(u);               // exact original logit
        int c = (int)(idx >> 16);                   // HW == 2^16
        int rem = (int)(idx & 0xFFFFu);
        const float* xb = x + (size_t)slice * SLICE_STRIDE;
        float ysf = (float)(rem >> 8);
        float xsf = (float)(rem & 255);
        float offx = xb[3 * HW + rem];
        float offy = xb[4 * HW + rem];
        float bw = xb[5 * HW + rem] * 4.0f;
        float bh = xb[6 * HW + rem] * 4.0f;
        float cx = (xsf + offx) * 4.0f;
        float cy = (ysf + offy) * 4.0f;
        bxs4[t] = make_float4(cx - bw * 0.5f, cy - bh * 0.5f,
                              cx + bw * 0.5f, cy + bh * 0.5f);
        float sg = 1.0f / (1.0f + expf(-z));
        scs[t] = (sg > 0.1f) ? sg : 0.0f;
        cl[t] = (float)c;
    }
    __syncthreads();

    // ---- phase B: wave 0, virtual-position soft-NMS ----
    if (t < 64) {
        float X1[4], Y1[4], X2[4], Y2[4], SC[4], CL4[4], AR[4];
        unsigned CP[4];
        #pragma unroll
        for (int sl = 0; sl < 4; ++sl) {
            int p = sl * 64 + t;
            int q = (p < NBOX) ? p : 0;
            float4 bb = bxs4[q];
            X1[sl] = bb.x; Y1[sl] = bb.y; X2[sl] = bb.z; Y2[sl] = bb.w;
            SC[sl] = (p < NBOX) ? scs[q] : 0.0f;    // phantoms: score 0
            CL4[sl] = cl[q];
            CP[sl] = (unsigned)p;                   // phantoms: cpos 200..255
            // round-invariant (boxes immutable); expression verbatim
            AR[sl] = (X2[sl] - X1[sl] + 1.0f) * (Y2[sl] - Y1[sl] + 1.0f);
        }

        for (int i = 0; i < NBOX; ++i) {
            const unsigned ui = (unsigned)i;
            // 64-bit key (score bits, ~((cpos<<8)|orig)); mask cpos>=i.
            // Phantoms keep cpos>=200 forever -> winner is always real.
            unsigned long long loc = 0ull;
            #pragma unroll
            for (int sl = 0; sl < 4; ++sl) {
                unsigned cd = ~((CP[sl] << 8) | (unsigned)(sl * 64 + t));
                unsigned long long k =
                    ((unsigned long long)__float_as_uint(SC[sl]) << 32) | cd;
                if (CP[sl] >= ui && k > loc) loc = k;
            }
            unsigned long long kmax = wave_umax64(loc);

            // Exact early-out: if the max remaining score is +0, every later
            // round is a fixpoint (winner = min cpos = i, swap(i,i), decay
            // multiplies zeros) -> state frozen. Break is bit-exact.
            if ((unsigned)(kmax >> 32) == 0u) break;

            unsigned w32 = ~((unsigned)kmax);       // (m<<8)|worig
            unsigned m = w32 >> 8;                  // current position of max
            int worig = (int)(w32 & 0xFFu);         // original slot (<200)
            int lane_m = worig & 63, slot_m = worig >> 6;

            // pivot gather from registers (readlane; no LDS in the chain)
            float pvx1 = lane_getf(X1, slot_m, lane_m);
            float pvy1 = lane_getf(Y1, slot_m, lane_m);
            float pvx2 = lane_getf(X2, slot_m, lane_m);
            float pvy2 = lane_getf(Y2, slot_m, lane_m);
            float area_i = lane_getf(AR, slot_m, lane_m);   // == verbatim expr

            // virtual swap: pos i <-> pos m
            #pragma unroll
            for (int sl = 0; sl < 4; ++sl) {
                unsigned cp = CP[sl];
                unsigned ncp = (cp == ui) ? m : cp;
                ncp = (cp == m) ? ui : ncp;
                CP[sl] = ncp;
            }

            // gaussian decay for current positions > i (formulas verbatim)
            #pragma unroll
            for (int sl = 0; sl < 4; ++sl) {
                int p = sl * 64 + t;
                if ((p < NBOX) && (CP[sl] > ui)) {
                    float x1 = X1[sl], y1 = Y1[sl], x2 = X2[sl], y2 = Y2[sl];
                    float xx1 = fmaxf(pvx1, x1);
                    float yy1 = fmaxf(pvy1, y1);
                    float xx2 = fminf(pvx2, x2);
                    float yy2 = fminf(pvy2, y2);
                    float inter = fmaxf(0.0f, xx2 - xx1 + 1.0f) *
                                  fmaxf(0.0f, yy2 - yy1 + 1.0f);
                    float iou = inter / (area_i + AR[sl] - inter);
                    float w = expf(-(iou * iou) / 0.5f);
                    SC[sl] = w * SC[sl];
                }
            }
        }

        // ---- write outputs: box with final cpos q lands at position q ----
        float* ob  = out + (size_t)b * NBOX * 4;
        float* oc  = out + (size_t)NBATCH * NBOX * 4 + b * NBOX;
        float* os  = out + (size_t)NBATCH * NBOX * 5 + b * NBOX;
        float* okp = out + (size_t)NBATCH * NBOX * 6 + b * NBOX;
        #pragma unroll
        for (int sl = 0; sl < 4; ++sl) {
            int p = sl * 64 + t;
            if (p < NBOX) {
                unsigned q = CP[sl];
                ob[q * 4 + 0] = X1[sl];
                ob[q * 4 + 1] = Y1[sl];
                ob[q * 4 + 2] = X2[sl];
                ob[q * 4 + 3] = Y2[sl];
                oc[q]  = CL4[sl];
                os[q]  = SC[sl];
                okp[q] = (SC[sl] > 0.1f) ? 1.0f : 0.0f;
            }
        }
    }
}

// ===========================================================================
// FALLBACK PATH (round-2 verified kernels, verbatim) — used if ws too small
// ===========================================================================
__global__ __launch_bounds__(1024) void ktopk(const float* __restrict__ x,
                                              float* __restrict__ out) {
    __shared__ unsigned hist[4096];
    __shared__ unsigned long long cand[CAP];
    __shared__ int shB, shB2;
    __shared__ unsigned shAbove, shNcand, shNc;

    const int slice = blockIdx.x;
    const int b = slice >> 1, s = slice & 1;
    const int t = threadIdx.x;
    const float* xb = x + (size_t)slice * SLICE_STRIDE;
    const float4* xb4 = (const float4*)xb;
    const int N4 = HM / 4;

    if (t == 0) { shB = 0; shB2 = 0; shAbove = 0u; shNcand = 0u; shNc = 0u; }
    for (int i = t; i < 4096; i += 1024) hist[i] = 0u;
    __syncthreads();

    for (int i = t; i < N4; i += 1024) {
        float4 v = xb4[i];
        float a[4] = {v.x, v.y, v.z, v.w};
        #pragma unroll
        for (int c_ = 0; c_ < 4; ++c_) {
            unsigned vk = fkey(a[c_]);
            atomicAdd(&hist[vk >> 20], 1u);
        }
    }
    __syncthreads();

    {
        unsigned* tmp = (unsigned*)cand;
        unsigned* src = hist;
        unsigned* dst = tmp;
        for (int d = 1; d < 4096; d <<= 1) {
            for (int i = t; i < 4096; i += 1024) {
                unsigned v = src[i];
                if (i + d < 4096) v += src[i + d];
                dst[i] = v;
            }
            __syncthreads();
            unsigned* sw = src; src = dst; dst = sw;
        }
        for (int i = t; i < 4096; i += 1024) {
            unsigned sb = src[i];
            unsigned sn = (i < 4095) ? src[i + 1] : 0u;
            if (sb >= TOPK && sn < TOPK) { shB = i; shAbove = sn; shNcand = sb; }
        }
        __syncthreads();
    }

    const bool refine = (shNcand > CAP);
    if (refine) {
        for (int i = t; i < 4096; i += 1024) hist[i] = 0u;
        __syncthreads();
        const unsigned Bv = (unsigned)shB;
        for (int i = t; i < N4; i += 1024) {
            float4 v = xb4[i];
            float a[4] = {v.x, v.y, v.z, v.w};
            #pragma unroll
            for (int c_ = 0; c_ < 4; ++c_) {
                unsigned vk = fkey(a[c_]);
                if ((vk >> 20) == Bv) atomicAdd(&hist[(vk >> 8) & 0xFFFu], 1u);
            }
        }
        __syncthreads();
        if (t == 0) {
            unsigned need = TOPK - shAbove, cum = 0u;
            int b2 = 4095;
            for (; b2 >= 0; --b2) { cum += hist[b2]; if (cum >= need) break; }
            shB2 = (b2 < 0) ? 0 : b2;
            shNcand = shAbove + cum;
        }
        __syncthreads();
    }

    {
        const unsigned Bv = (unsigned)shB;
        const unsigned B2v = refine ? (unsigned)shB2 : 0u;
        for (int i = t; i < N4; i += 1024) {
            float4 v = xb4[i];
            float a[4] = {v.x, v.y, v.z, v.w};
            #pragma unroll
            for (int c_ = 0; c_ < 4; ++c_) {
                unsigned vk = fkey(a[c_]);
                unsigned bin = vk >> 20;
                bool q = refine ? (bin > Bv || (bin == Bv && ((vk >> 8) & 0xFFFu) >= B2v))
                                : (bin >= Bv);
                if (q) {
                    unsigned pos = atomicAdd(&shNc, 1u);
                    if (pos < CAP)
                        cand[pos] = ((unsigned long long)vk << 32) |
                                    (unsigned)~(unsigned)(i * 4 + c_);
                }
            }
        }
        __syncthreads();
    }

    unsigned nc = shNc; if (nc > CAP) nc = CAP;
    int P = 128; while (P < (int)nc) P <<= 1;
    for (int i = (int)nc + t; i < P; i += 1024) cand[i] = 0ull;
    __syncthreads();
    for (int k = 2; k <= P; k <<= 1) {
        for (int j = k >> 1; j > 0; j >>= 1) {
            for (int i = t; i < P; i += 1024) {
                int ixj = i ^ j;
                if (ixj > i) {
                    unsigned long long a = cand[i], c2 = cand[ixj];
                    bool sw = ((i & k) == 0) ? (a < c2) : (a > c2);
                    if (sw) { cand[i] = c2; cand[ixj] = a; }
                }
            }
            __syncthreads();
        }
    }

    if (t < TOPK) {
        unsigned long long K = cand[t];
        unsigned vk = (unsigned)(K >> 32);
        unsigned idx = ~((unsigned)K);
        unsigned u = (vk & 0x80000000u) ? (vk & 0x7FFFFFFFu) : ~vk;
        float z = __uint_as_float(u);
        int c = (int)(idx >> 16);
        int rem = (int)(idx & 0xFFFFu);
        float ysf = (float)(rem >> 8);
        float xsf = (float)(rem & 255);
        float offx = xb[3 * HW + rem];
        float offy = xb[4 * HW + rem];
        float bw = xb[5 * HW + rem] * 4.0f;
        float bh = xb[6 * HW + rem] * 4.0f;
        float cx = (xsf + offx) * 4.0f;
        float cy = (ysf + offy) * 4.0f;
        int slot = s * TOPK + t;
        float* ob = out + (size_t)b * NBOX * 4;
        float* oc = out + (size_t)NBATCH * NBOX * 4 + b * NBOX;
        float* os = out + (size_t)NBATCH * NBOX * 5 + b * NBOX;
        ob[slot * 4 + 0] = cx - bw * 0.5f;
        ob[slot * 4 + 1] = cy - bh * 0.5f;
        ob[slot * 4 + 2] = cx + bw * 0.5f;
        ob[slot * 4 + 3] = cy + bh * 0.5f;
        float sg = 1.0f / (1.0f + expf(-z));
        os[slot] = (sg > 0.1f) ? sg : 0.0f;
        oc[slot] = (float)c;
    }
}

__global__ __launch_bounds__(64) void knms(float* __restrict__ out) {
    __shared__ float bxs[NBOX][4];
    __shared__ float scs[NBOX];
    __shared__ float cl[NBOX];

    const int b = blockIdx.x, t = threadIdx.x;
    float* ob  = out + (size_t)b * NBOX * 4;
    float* oc  = out + (size_t)NBATCH * NBOX * 4 + b * NBOX;
    float* os  = out + (size_t)NBATCH * NBOX * 5 + b * NBOX;
    float* okp = out + (size_t)NBATCH * NBOX * 6 + b * NBOX;

    for (int p = t; p < NBOX; p += 64) {
        bxs[p][0] = ob[p * 4 + 0];
        bxs[p][1] = ob[p * 4 + 1];
        bxs[p][2] = ob[p * 4 + 2];
        bxs[p][3] = ob[p * 4 + 3];
        scs[p] = os[p];
        cl[p]  = oc[p];
    }
    __syncthreads();

    unsigned long long local = 0ull;
    for (int p = t; p < NBOX; p += 64) {
        unsigned long long k =
            ((unsigned long long)__float_as_uint(scs[p]) << 32) | (unsigned)~(unsigned)p;
        if (k > local) local = k;
    }
    #pragma unroll
    for (int off = 32; off > 0; off >>= 1) {
        unsigned long long o = __shfl_xor(local, off);
        if (o > local) local = o;
    }
    unsigned long long kmax = local;

    for (int i = 0; i < NBOX; ++i) {
        int m = (int)(~((unsigned)kmax));
        if (t == 0 && m != i) {
            #pragma unroll
            for (int k = 0; k < 4; ++k) {
                float tmp = bxs[i][k]; bxs[i][k] = bxs[m][k]; bxs[m][k] = tmp;
            }
            float ts = scs[i]; scs[i] = scs[m]; scs[m] = ts;
            float tc = cl[i];  cl[i]  = cl[m];  cl[m]  = tc;
        }
        __syncthreads();

        float b0 = bxs[i][0], b1 = bxs[i][1], b2 = bxs[i][2], b3 = bxs[i][3];
        float area_i = (b2 - b0 + 1.0f) * (b3 - b1 + 1.0f);

        local = 0ull;
        for (int p = i + 1 + t; p < NBOX; p += 64) {
            float x1 = bxs[p][0], y1 = bxs[p][1], x2 = bxs[p][2], y2 = bxs[p][3];
            float areas = (x2 - x1 + 1.0f) * (y2 - y1 + 1.0f);
            float xx1 = fmaxf(b0, x1);
            float yy1 = fmaxf(b1, y1);
            float xx2 = fminf(b2, x2);
            float yy2 = fminf(b3, y2);
            float inter = fmaxf(0.0f, xx2 - xx1 + 1.0f) * fmaxf(0.0f, yy2 - yy1 + 1.0f);
            float iou = inter / (area_i + areas - inter);
            float w = expf(-(iou * iou) / 0.5f);
            float ns = w * scs[p];
            scs[p] = ns;
            unsigned long long k =
                ((unsigned long long)__float_as_uint(ns) << 32) | (unsigned)~(unsigned)p;
            if (k > local) local = k;
        }
        __syncthreads();
        #pragma unroll
        for (int off = 32; off > 0; off >>= 1) {
            unsigned long long o = __shfl_xor(local, off);
            if (o > local) local = o;
        }
        kmax = local;
    }
    __syncthreads();

    for (int p = t; p < NBOX; p += 64) {
        ob[p * 4 + 0] = bxs[p][0];
        ob[p * 4 + 1] = bxs[p][1];
        ob[p * 4 + 2] = bxs[p][2];
        ob[p * 4 + 3] = bxs[p][3];
        oc[p]  = cl[p];
        os[p]  = scs[p];
        okp[p] = (scs[p] > 0.1f) ? 1.0f : 0.0f;
    }
}

extern "C" void kernel_launch(void* const* d_in, const int* in_sizes, int n_in,
                              void* d_out, int out_size, void* d_ws, size_t ws_size,
                              hipStream_t stream) {
    const float* x = (const float*)d_in[0];
    float* out = (float*)d_out;
    if (d_ws != nullptr && ws_size >= WS_NEED) {
        kslice<<<2 * NBATCH, 1024, 0, stream>>>(x, (unsigned long long*)d_ws);
        knms5<<<NBATCH, 256, 0, stream>>>(x, (const unsigned long long*)d_ws, out);
    } else {
        ktopk<<<2 * NBATCH, 1024, 0, stream>>>(x, out);
        knms<<<NBATCH, 64, 0, stream>>>(out);
    }
}

// Round 7
// 274.254 us; speedup vs baseline: 1.2439x; 1.2439x over previous
//
#include <hip/hip_runtime.h>
#include <math.h>

#define TOPK 100
#define HW 65536                   // 256*256
#define SLICE_STRIDE (7*HW)        // 458752
#define NBATCH 32
#define NBOX 200
#define HM (3*HW)                  // 196608 heatmap elems per slice
#define CAP 4096                   // candidate cap (no-ws fallback path)
#define NPART 4                    // collect parts per slice
#define PPART 128                  // key slots per part
#define KEYS_BASE 256              // u64 index where keys start (2048B: cnt region)
#define WS_NEED ((size_t)(2048 + 64 * NPART * PPART * 8))
#define TKEYS 0xC0400000u          // fkey(3.0f): collect threshold.
                                   // N(0,1): per-part (49152 elems) mean 66.3,
                                   // sigma 8.1 -> P(>128) ~ 7.6 sigma; per-slice
                                   // total 265 +- 16 -> P(<100) ~ 10 sigma.
                                   // Exact in-kernel fallback guards regardless.

// Order-preserving float->uint key: f1 > f2  <=>  key(f1) > key(f2)
__device__ __forceinline__ unsigned fkey(float f) {
    unsigned u = __float_as_uint(f);
    return (u & 0x80000000u) ? ~u : (u | 0x80000000u);
}

// Runtime-slot select over a 4-entry register array with constant indices only
__device__ __forceinline__ float sel4(const float a[4], int s) {
    float r = a[0];
    r = (s == 1) ? a[1] : r;
    r = (s == 2) ? a[2] : r;
    r = (s == 3) ? a[3] : r;
    return r;
}

// ---------------------------------------------------------------------------
// Wave64 u64 max-reduce via DPP (verbatim from round-4..6 verified kernels).
// ---------------------------------------------------------------------------
#if defined(__has_builtin) && __has_builtin(__builtin_amdgcn_update_dpp)
#define DPP64_STEP(ctrl)                                                        \
    {                                                                           \
        unsigned lo = (unsigned)x, hi = (unsigned)(x >> 32);                    \
        unsigned olo = (unsigned)__builtin_amdgcn_update_dpp((int)lo, (int)lo,  \
                                                             (ctrl), 0xF, 0xF, false); \
        unsigned ohi = (unsigned)__builtin_amdgcn_update_dpp((int)hi, (int)hi,  \
                                                             (ctrl), 0xF, 0xF, false); \
        unsigned long long o = ((unsigned long long)ohi << 32) | olo;           \
        x = (o > x) ? o : x;                                                    \
    }
__device__ __forceinline__ unsigned long long wave_umax64(unsigned long long x) {
    DPP64_STEP(0x111)   // row_shr:1
    DPP64_STEP(0x112)   // row_shr:2
    DPP64_STEP(0x114)   // row_shr:4
    DPP64_STEP(0x118)   // row_shr:8
    DPP64_STEP(0x142)   // row_bcast:15
    DPP64_STEP(0x143)   // row_bcast:31
    unsigned rlo = (unsigned)__builtin_amdgcn_readlane((int)(unsigned)x, 63);
    unsigned rhi = (unsigned)__builtin_amdgcn_readlane((int)(unsigned)(x >> 32), 63);
    return ((unsigned long long)rhi << 32) | rlo;
}
__device__ __forceinline__ float lane_getf(const float a[4], int slot, int lane) {
    return __uint_as_float((unsigned)__builtin_amdgcn_readlane(
        (int)__float_as_uint(sel4(a, slot)), lane));
}
#else
__device__ __forceinline__ unsigned long long wave_umax64(unsigned long long x) {
    #pragma unroll
    for (int off = 32; off > 0; off >>= 1) {
        unsigned long long o = __shfl_xor(x, off);
        if (o > x) x = o;
    }
    return x;
}
__device__ __forceinline__ float lane_getf(const float a[4], int slot, int lane) {
    return __shfl(sel4(a, slot), lane);
}
#endif

// ===========================================================================
// Kernel 1: threshold collect. 256 blocks x 1024 threads; block (slice,part)
// owns cnt[slice*4+part] and keys[slice*512 + part*128 + ...] exclusively —
// no cross-block atomics, no pre-zeroing (reads are guarded by the count).
// Key = (fkey(z) << 32) | ~idx — the verified ordering of rounds 2-6.
// ===========================================================================
__global__ __launch_bounds__(1024) void kcollect(const float* __restrict__ x,
                                                 unsigned long long* __restrict__ ws) {
    __shared__ unsigned shCnt;
    const int bid = blockIdx.x;
    const int slice = bid >> 2, part = bid & 3;
    const int t = threadIdx.x;
    const float* xb = x + (size_t)slice * SLICE_STRIDE;
    const float4* xb4 = (const float4*)xb;
    unsigned* cnt = (unsigned*)ws;                          // u32[64*4]
    unsigned long long* keys = ws + KEYS_BASE;

    if (t == 0) shCnt = 0u;
    __syncthreads();

    const int i0 = part * (HM / 4 / NPART);                 // 12288 float4/part
    const int i1 = i0 + (HM / 4 / NPART);
    for (int i = i0 + t; i < i1; i += 1024) {
        float4 v = xb4[i];
        float a[4] = {v.x, v.y, v.z, v.w};
        #pragma unroll
        for (int q = 0; q < 4; ++q) {
            unsigned vk = fkey(a[q]);
            if (vk >= TKEYS) {
                unsigned pos = atomicAdd(&shCnt, 1u);
                if (pos < PPART)
                    keys[(size_t)slice * (NPART * PPART) + part * PPART + pos] =
                        ((unsigned long long)vk << 32) |
                        (unsigned)~(unsigned)(i * 4 + q);
            }
        }
    }
    __syncthreads();
    if (t == 0) cnt[slice * NPART + part] = shCnt;          // raw count (may >PPART)
}

// ---------------------------------------------------------------------------
// Exact fallback selection (round-0 verified 100-pass argmax, widened to
// 1024 threads). Never triggers for this input; guards correctness.
// ---------------------------------------------------------------------------
__device__ void fb_select(const float* xb, unsigned long long* fkrow,
                          unsigned* selmask, float* rv, int* ri, int t) {
    for (int i = t; i < HM / 32; i += 1024) selmask[i] = 0u;
    __syncthreads();
    for (int r = 0; r < TOPK; ++r) {
        float bv = -INFINITY; int bi = 0x7FFFFFFF;
        for (int i = t; i < HM; i += 1024) {
            if (!((selmask[i >> 5] >> (i & 31)) & 1u)) {
                float v = xb[i];
                if (v > bv || (v == bv && i < bi)) { bv = v; bi = i; }
            }
        }
        rv[t] = bv; ri[t] = bi;
        __syncthreads();
        for (int off = 512; off > 0; off >>= 1) {
            if (t < off) {
                float ov = rv[t + off]; int oi = ri[t + off];
                if (ov > rv[t] || (ov == rv[t] && oi < ri[t])) { rv[t] = ov; ri[t] = oi; }
            }
            __syncthreads();
        }
        if (t == 0) {
            int w = ri[0];
            selmask[w >> 5] |= (1u << (w & 31));
            fkrow[r] = ((unsigned long long)fkey(rv[0]) << 32) |
                       (unsigned)~(unsigned)w;
        }
        __syncthreads();
    }
}

// ===========================================================================
// Kernel 2: 32 blocks x 1024 threads. Phase A: per half-block, gather the
// slice's <=512 collected keys, bitonic-sort (desc), decode top-100.
// Phase B: wave-0 virtual-position soft-NMS (round-6 verified structure)
// with a decay-skip ballot: when no active box overlaps the pivot
// (all inter == 0 -> reference w = expf(-0.0f) = 1.0f exactly), the
// iou/exp/score-update chain is skipped bit-exactly.
// ===========================================================================
__global__ __launch_bounds__(1024) void knms6(const float* __restrict__ x,
                                              const unsigned long long* __restrict__ ws,
                                              float* __restrict__ out) {
    __shared__ unsigned long long shpool64[4096];   // 32 KB union
    __shared__ unsigned long long fk[2][TOPK];
    __shared__ float4 bxs4[NBOX];
    __shared__ float scs[NBOX];
    __shared__ float cl[NBOX];
    __shared__ int badf[2];

    unsigned long long* skey = shpool64;            // [2][512]
    unsigned* selmask = (unsigned*)shpool64;        // fallback: [6144]
    float* rv = (float*)(selmask + 6144);           // fallback: [1024]
    int* ri = (int*)(selmask + 7168);               // fallback: [1024]

    const int b = blockIdx.x, t = threadIdx.x;
    const unsigned* cnt = (const unsigned*)ws;
    const unsigned long long* keys = ws + KEYS_BASE;

    if (t < 2) {
        unsigned tot = 0; int bad = 0;
        for (int p8 = 0; p8 < NPART; ++p8) {
            unsigned c = cnt[(2 * b + t) * NPART + p8];
            tot += c;
            if (c > PPART) bad = 1;
        }
        if (tot < TOPK) bad = 1;
        badf[t] = bad;
    }
    __syncthreads();

    if (badf[0]) fb_select(x + (size_t)(2 * b + 0) * SLICE_STRIDE, fk[0],
                           selmask, rv, ri, t);
    if (badf[1]) fb_select(x + (size_t)(2 * b + 1) * SLICE_STRIDE, fk[1],
                           selmask, rv, ri, t);

    // ---- phase A: gather + bitonic sort 512 per half (parallel halves) ----
    const int half = t >> 9, tt = t & 511;
    const int slice = 2 * b + half;
    {
        int part = tt >> 7, off = tt & 127;
        unsigned c = cnt[slice * NPART + part];
        bool valid = (!badf[half]) && ((unsigned)off < c);
        skey[half * 512 + tt] = valid
            ? keys[(size_t)slice * (NPART * PPART) + part * PPART + off] : 0ull;
    }
    __syncthreads();
    for (int k = 2; k <= 512; k <<= 1) {
        for (int j = k >> 1; j > 0; j >>= 1) {
            int i = tt, ixj = i ^ j;
            if (ixj > i) {
                unsigned long long a = skey[half * 512 + i];
                unsigned long long c2 = skey[half * 512 + ixj];
                bool sw = ((i & k) == 0) ? (a < c2) : (a > c2);
                if (sw) { skey[half * 512 + i] = c2; skey[half * 512 + ixj] = a; }
            }
            __syncthreads();
        }
    }

    // ---- decode top-100 per slice (formulas verbatim, verified r2-r6) ----
    if (t < NBOX) {
        const int sB = t / TOPK, rank = t - sB * TOPK;
        const int sl2 = 2 * b + sB;
        unsigned long long K = badf[sB] ? fk[sB][rank] : skey[sB * 512 + rank];
        unsigned vk = (unsigned)(K >> 32);
        unsigned idx = ~((unsigned)K);
        unsigned u = (vk & 0x80000000u) ? (vk & 0x7FFFFFFFu) : ~vk;
        float z = __uint_as_float(u);               // exact original logit
        int c = (int)(idx >> 16);                   // HW == 2^16
        int rem = (int)(idx & 0xFFFFu);
        const float* xb = x + (size_t)sl2 * SLICE_STRIDE;
        float ysf = (float)(rem >> 8);
        float xsf = (float)(rem & 255);
        float offx = xb[3 * HW + rem];
        float offy = xb[4 * HW + rem];
        float bw = xb[5 * HW + rem] * 4.0f;
        float bh = xb[6 * HW + rem] * 4.0f;
        float cx = (xsf + offx) * 4.0f;
        float cy = (ysf + offy) * 4.0f;
        bxs4[t] = make_float4(cx - bw * 0.5f, cy - bh * 0.5f,
                              cx + bw * 0.5f, cy + bh * 0.5f);
        float sg = 1.0f / (1.0f + expf(-z));
        scs[t] = (sg > 0.1f) ? sg : 0.0f;
        cl[t] = (float)c;
    }
    __syncthreads();

    // ---- phase B: wave 0, virtual-position soft-NMS with decay-skip ----
    if (t < 64) {
        float X1[4], Y1[4], X2[4], Y2[4], SC[4], CL4[4], AR[4];
        unsigned CP[4];
        #pragma unroll
        for (int sl = 0; sl < 4; ++sl) {
            int p = sl * 64 + t;
            int q = (p < NBOX) ? p : 0;
            float4 bb = bxs4[q];
            X1[sl] = bb.x; Y1[sl] = bb.y; X2[sl] = bb.z; Y2[sl] = bb.w;
            SC[sl] = (p < NBOX) ? scs[q] : 0.0f;    // phantoms: score 0
            CL4[sl] = cl[q];
            CP[sl] = (unsigned)p;                   // phantoms: cpos 200..255
            AR[sl] = (X2[sl] - X1[sl] + 1.0f) * (Y2[sl] - Y1[sl] + 1.0f);
        }

        for (int i = 0; i < NBOX; ++i) {
            const unsigned ui = (unsigned)i;
            // 64-bit key (score bits, ~((cpos<<8)|orig)); mask cpos>=i.
            // Real boxes always occupy positions 0..199 -> winner is real.
            unsigned long long loc = 0ull;
            #pragma unroll
            for (int sl = 0; sl < 4; ++sl) {
                unsigned cd = ~((CP[sl] << 8) | (unsigned)(sl * 64 + t));
                unsigned long long k =
                    ((unsigned long long)__float_as_uint(SC[sl]) << 32) | cd;
                if (CP[sl] >= ui && k > loc) loc = k;
            }
            unsigned long long kmax = wave_umax64(loc);

            // exact early-out (verified r6): max remaining score +0 -> frozen
            if ((unsigned)(kmax >> 32) == 0u) break;

            unsigned w32 = ~((unsigned)kmax);       // (m<<8)|worig
            unsigned m = w32 >> 8;
            int worig = (int)(w32 & 0xFFu);
            int lane_m = worig & 63, slot_m = worig >> 6;

            float pvx1 = lane_getf(X1, slot_m, lane_m);
            float pvy1 = lane_getf(Y1, slot_m, lane_m);
            float pvx2 = lane_getf(X2, slot_m, lane_m);
            float pvy2 = lane_getf(Y2, slot_m, lane_m);
            float area_i = lane_getf(AR, slot_m, lane_m);

            // virtual swap: pos i <-> pos m
            #pragma unroll
            for (int sl = 0; sl < 4; ++sl) {
                unsigned cp = CP[sl];
                unsigned ncp = (cp == ui) ? m : cp;
                ncp = (cp == m) ? ui : ncp;
                CP[sl] = ncp;
            }

            // intersection prefix + overlap ballot
            float intr[4]; bool anyp = false;
            #pragma unroll
            for (int sl = 0; sl < 4; ++sl) {
                int p = sl * 64 + t;
                bool act = (p < NBOX) && (CP[sl] > ui);
                float xx1 = fmaxf(pvx1, X1[sl]);
                float yy1 = fmaxf(pvy1, Y1[sl]);
                float xx2 = fminf(pvx2, X2[sl]);
                float yy2 = fminf(pvy2, Y2[sl]);
                float inter = fmaxf(0.0f, xx2 - xx1 + 1.0f) *
                              fmaxf(0.0f, yy2 - yy1 + 1.0f);
                intr[sl] = inter;
                anyp |= (act && inter != 0.0f);
            }
            // skip is bit-exact: inter==0 -> iou=0 -> w=expf(-0.0f)=1.0f -> SC unchanged
            if (__ballot(anyp) != 0ull) {
                #pragma unroll
                for (int sl = 0; sl < 4; ++sl) {
                    int p = sl * 64 + t;
                    if ((p < NBOX) && (CP[sl] > ui)) {
                        float iou = intr[sl] / (area_i + AR[sl] - intr[sl]);
                        float w = expf(-(iou * iou) / 0.5f);
                        SC[sl] = w * SC[sl];
                    }
                }
            }
        }

        // ---- write outputs: box with final cpos q lands at position q ----
        float* ob  = out + (size_t)b * NBOX * 4;
        float* oc  = out + (size_t)NBATCH * NBOX * 4 + b * NBOX;
        float* os  = out + (size_t)NBATCH * NBOX * 5 + b * NBOX;
        float* okp = out + (size_t)NBATCH * NBOX * 6 + b * NBOX;
        #pragma unroll
        for (int sl = 0; sl < 4; ++sl) {
            int p = sl * 64 + t;
            if (p < NBOX) {
                unsigned q = CP[sl];
                ob[q * 4 + 0] = X1[sl];
                ob[q * 4 + 1] = Y1[sl];
                ob[q * 4 + 2] = X2[sl];
                ob[q * 4 + 3] = Y2[sl];
                oc[q]  = CL4[sl];
                os[q]  = SC[sl];
                okp[q] = (SC[sl] > 0.1f) ? 1.0f : 0.0f;
            }
        }
    }
}

// ===========================================================================
// FALLBACK PATH (round-2 verified kernels, verbatim) — used if ws too small
// ===========================================================================
__global__ __launch_bounds__(1024) void ktopk(const float* __restrict__ x,
                                              float* __restrict__ out) {
    __shared__ unsigned hist[4096];
    __shared__ unsigned long long cand[CAP];
    __shared__ int shB, shB2;
    __shared__ unsigned shAbove, shNcand, shNc;

    const int slice = blockIdx.x;
    const int b = slice >> 1, s = slice & 1;
    const int t = threadIdx.x;
    const float* xb = x + (size_t)slice * SLICE_STRIDE;
    const float4* xb4 = (const float4*)xb;
    const int N4 = HM / 4;

    if (t == 0) { shB = 0; shB2 = 0; shAbove = 0u; shNcand = 0u; shNc = 0u; }
    for (int i = t; i < 4096; i += 1024) hist[i] = 0u;
    __syncthreads();

    for (int i = t; i < N4; i += 1024) {
        float4 v = xb4[i];
        float a[4] = {v.x, v.y, v.z, v.w};
        #pragma unroll
        for (int c_ = 0; c_ < 4; ++c_) {
            unsigned vk = fkey(a[c_]);
            atomicAdd(&hist[vk >> 20], 1u);
        }
    }
    __syncthreads();

    {
        unsigned* tmp = (unsigned*)cand;
        unsigned* src = hist;
        unsigned* dst = tmp;
        for (int d = 1; d < 4096; d <<= 1) {
            for (int i = t; i < 4096; i += 1024) {
                unsigned v = src[i];
                if (i + d < 4096) v += src[i + d];
                dst[i] = v;
            }
            __syncthreads();
            unsigned* sw = src; src = dst; dst = sw;
        }
        for (int i = t; i < 4096; i += 1024) {
            unsigned sb = src[i];
            unsigned sn = (i < 4095) ? src[i + 1] : 0u;
            if (sb >= TOPK && sn < TOPK) { shB = i; shAbove = sn; shNcand = sb; }
        }
        __syncthreads();
    }

    const bool refine = (shNcand > CAP);
    if (refine) {
        for (int i = t; i < 4096; i += 1024) hist[i] = 0u;
        __syncthreads();
        const unsigned Bv = (unsigned)shB;
        for (int i = t; i < N4; i += 1024) {
            float4 v = xb4[i];
            float a[4] = {v.x, v.y, v.z, v.w};
            #pragma unroll
            for (int c_ = 0; c_ < 4; ++c_) {
                unsigned vk = fkey(a[c_]);
                if ((vk >> 20) == Bv) atomicAdd(&hist[(vk >> 8) & 0xFFFu], 1u);
            }
        }
        __syncthreads();
        if (t == 0) {
            unsigned need = TOPK - shAbove, cum = 0u;
            int b2 = 4095;
            for (; b2 >= 0; --b2) { cum += hist[b2]; if (cum >= need) break; }
            shB2 = (b2 < 0) ? 0 : b2;
            shNcand = shAbove + cum;
        }
        __syncthreads();
    }

    {
        const unsigned Bv = (unsigned)shB;
        const unsigned B2v = refine ? (unsigned)shB2 : 0u;
        for (int i = t; i < N4; i += 1024) {
            float4 v = xb4[i];
            float a[4] = {v.x, v.y, v.z, v.w};
            #pragma unroll
            for (int c_ = 0; c_ < 4; ++c_) {
                unsigned vk = fkey(a[c_]);
                unsigned bin = vk >> 20;
                bool q = refine ? (bin > Bv || (bin == Bv && ((vk >> 8) & 0xFFFu) >= B2v))
                                : (bin >= Bv);
                if (q) {
                    unsigned pos = atomicAdd(&shNc, 1u);
                    if (pos < CAP)
                        cand[pos] = ((unsigned long long)vk << 32) |
                                    (unsigned)~(unsigned)(i * 4 + c_);
                }
            }
        }
        __syncthreads();
    }

    unsigned nc = shNc; if (nc > CAP) nc = CAP;
    int P = 128; while (P < (int)nc) P <<= 1;
    for (int i = (int)nc + t; i < P; i += 1024) cand[i] = 0ull;
    __syncthreads();
    for (int k = 2; k <= P; k <<= 1) {
        for (int j = k >> 1; j > 0; j >>= 1) {
            for (int i = t; i < P; i += 1024) {
                int ixj = i ^ j;
                if (ixj > i) {
                    unsigned long long a = cand[i], c2 = cand[ixj];
                    bool sw = ((i & k) == 0) ? (a < c2) : (a > c2);
                    if (sw) { cand[i] = c2; cand[ixj] = a; }
                }
            }
            __syncthreads();
        }
    }

    if (t < TOPK) {
        unsigned long long K = cand[t];
        unsigned vk = (unsigned)(K >> 32);
        unsigned idx = ~((unsigned)K);
        unsigned u = (vk & 0x80000000u) ? (vk & 0x7FFFFFFFu) : ~vk;
        float z = __uint_as_float(u);
        int c = (int)(idx >> 16);
        int rem = (int)(idx & 0xFFFFu);
        float ysf = (float)(rem >> 8);
        float xsf = (float)(rem & 255);
        float offx = xb[3 * HW + rem];
        float offy = xb[4 * HW + rem];
        float bw = xb[5 * HW + rem] * 4.0f;
        float bh = xb[6 * HW + rem] * 4.0f;
        float cx = (xsf + offx) * 4.0f;
        float cy = (ysf + offy) * 4.0f;
        int slot = s * TOPK + t;
        float* ob = out + (size_t)b * NBOX * 4;
        float* oc = out + (size_t)NBATCH * NBOX * 4 + b * NBOX;
        float* os = out + (size_t)NBATCH * NBOX * 5 + b * NBOX;
        ob[slot * 4 + 0] = cx - bw * 0.5f;
        ob[slot * 4 + 1] = cy - bh * 0.5f;
        ob[slot * 4 + 2] = cx + bw * 0.5f;
        ob[slot * 4 + 3] = cy + bh * 0.5f;
        float sg = 1.0f / (1.0f + expf(-z));
        os[slot] = (sg > 0.1f) ? sg : 0.0f;
        oc[slot] = (float)c;
    }
}

__global__ __launch_bounds__(64) void knms(float* __restrict__ out) {
    __shared__ float bxs[NBOX][4];
    __shared__ float scs[NBOX];
    __shared__ float cl[NBOX];

    const int b = blockIdx.x, t = threadIdx.x;
    float* ob  = out + (size_t)b * NBOX * 4;
    float* oc  = out + (size_t)NBATCH * NBOX * 4 + b * NBOX;
    float* os  = out + (size_t)NBATCH * NBOX * 5 + b * NBOX;
    float* okp = out + (size_t)NBATCH * NBOX * 6 + b * NBOX;

    for (int p = t; p < NBOX; p += 64) {
        bxs[p][0] = ob[p * 4 + 0];
        bxs[p][1] = ob[p * 4 + 1];
        bxs[p][2] = ob[p * 4 + 2];
        bxs[p][3] = ob[p * 4 + 3];
        scs[p] = os[p];
        cl[p]  = oc[p];
    }
    __syncthreads();

    unsigned long long local = 0ull;
    for (int p = t; p < NBOX; p += 64) {
        unsigned long long k =
            ((unsigned long long)__float_as_uint(scs[p]) << 32) | (unsigned)~(unsigned)p;
        if (k > local) local = k;
    }
    #pragma unroll
    for (int off = 32; off > 0; off >>= 1) {
        unsigned long long o = __shfl_xor(local, off);
        if (o > local) local = o;
    }
    unsigned long long kmax = local;

    for (int i = 0; i < NBOX; ++i) {
        int m = (int)(~((unsigned)kmax));
        if (t == 0 && m != i) {
            #pragma unroll
            for (int k = 0; k < 4; ++k) {
                float tmp = bxs[i][k]; bxs[i][k] = bxs[m][k]; bxs[m][k] = tmp;
            }
            float ts = scs[i]; scs[i] = scs[m]; scs[m] = ts;
            float tc = cl[i];  cl[i]  = cl[m];  cl[m]  = tc;
        }
        __syncthreads();

        float b0 = bxs[i][0], b1 = bxs[i][1], b2 = bxs[i][2], b3 = bxs[i][3];
        float area_i = (b2 - b0 + 1.0f) * (b3 - b1 + 1.0f);

        local = 0ull;
        for (int p = i + 1 + t; p < NBOX; p += 64) {
            float x1 = bxs[p][0], y1 = bxs[p][1], x2 = bxs[p][2], y2 = bxs[p][3];
            float areas = (x2 - x1 + 1.0f) * (y2 - y1 + 1.0f);
            float xx1 = fmaxf(b0, x1);
            float yy1 = fmaxf(b1, y1);
            float xx2 = fminf(b2, x2);
            float yy2 = fminf(b3, y2);
            float inter = fmaxf(0.0f, xx2 - xx1 + 1.0f) * fmaxf(0.0f, yy2 - yy1 + 1.0f);
            float iou = inter / (area_i + areas - inter);
            float w = expf(-(iou * iou) / 0.5f);
            float ns = w * scs[p];
            scs[p] = ns;
            unsigned long long k =
                ((unsigned long long)__float_as_uint(ns) << 32) | (unsigned)~(unsigned)p;
            if (k > local) local = k;
        }
        __syncthreads();
        #pragma unroll
        for (int off = 32; off > 0; off >>= 1) {
            unsigned long long o = __shfl_xor(local, off);
            if (o > local) local = o;
        }
        kmax = local;
    }
    __syncthreads();

    for (int p = t; p < NBOX; p += 64) {
        ob[p * 4 + 0] = bxs[p][0];
        ob[p * 4 + 1] = bxs[p][1];
        ob[p * 4 + 2] = bxs[p][2];
        ob[p * 4 + 3] = bxs[p][3];
        oc[p]  = cl[p];
        os[p]  = scs[p];
        okp[p] = (scs[p] > 0.1f) ? 1.0f : 0.0f;
    }
}

extern "C" void kernel_launch(void* const* d_in, const int* in_sizes, int n_in,
                              void* d_out, int out_size, void* d_ws, size_t ws_size,
                              hipStream_t stream) {
    const float* x = (const float*)d_in[0];
    float* out = (float*)d_out;
    if (d_ws != nullptr && ws_size >= WS_NEED) {
        kcollect<<<64 * NPART, 1024, 0, stream>>>(x, (unsigned long long*)d_ws);
        knms6<<<NBATCH, 1024, 0, stream>>>(x, (const unsigned long long*)d_ws, out);
    } else {
        ktopk<<<2 * NBATCH, 1024, 0, stream>>>(x, out);
        knms<<<NBATCH, 64, 0, stream>>>(out);
    }
}